// Round 1
// baseline (456.416 us; speedup 1.0000x reference)
//
#include <hip/hip_runtime.h>

// B=131072 indep LSTMs, T=40, H=40, in-dim 1, FC C=4 + argmax.
// R14 = R13 (411us) restructured for concurrency: 1 wave/SIMD x 4 in-flight
// sample-tiles ("chains") per wave, full 512-reg budget.
//  - R13 was latency-bound at 2 waves/SIMD (Occ 22%), capped by the 144-reg
//    per-wave copy of split-f16 weight fragments inside a 256-reg budget.
//  - Here ONE B copy serves 4 chains: concurrency/SIMD 2 -> 4 dependency
//    chains, B never duplicated. Per-sample math is IDENTICAL to R13
//    (same prep, same MFMA order, same activation algebra) -> absmax must
//    stay 4.882812e-4.
//  - 2 sequential groups x 4 chains = 128 samples/wave; grid = 256 blocks =
//    exactly 1 block/CU, zero tail. Prologue (B build) amortized 8x.
//  - LROW 68 -> 60 (same 2-way bank aliasing: 60%32=28 == -4 mod 32) so
//    4 waves x 4 tiles x 16 rows fits static LDS: 61440 B < 64 KB.

#define B_    131072
#define T_    40
#define H_    40
#define C_    4
#define BLK   256
#define WPB   4
#define NCH   4           // sample-tiles (chains) in flight per wave
#define NGRP  2           // sequential groups per wave
#define SPW   (NCH * 16)  // samples per wave per group = 64
#define SPB   (WPB * SPW * NGRP)   // 512 samples per block
#define LROW  60          // padded LDS row stride (floats); 60%32=28 -> 2-way only
#define TILEF (16 * LROW) // 960 floats per tile slice
#define NT    12          // 192 padded gate columns / 16
#define LOG2E 1.44269504088896340736f

typedef __fp16   fp16x2 __attribute__((ext_vector_type(2)));
typedef _Float16 half2v __attribute__((ext_vector_type(2)));
typedef _Float16 half4v __attribute__((ext_vector_type(4)));
typedef _Float16 half8v __attribute__((ext_vector_type(8)));
typedef float    f32x2  __attribute__((ext_vector_type(2)));
typedef float    f32x4  __attribute__((ext_vector_type(4)));

__device__ __forceinline__ float fexp2f(float v){ return __builtin_amdgcn_exp2f(v); }
__device__ __forceinline__ float frcpf (float v){ return __builtin_amdgcn_rcpf(v); }

__device__ __forceinline__ f32x2 fexp2v(f32x2 v){ return (f32x2){fexp2f(v[0]), fexp2f(v[1])}; }
__device__ __forceinline__ f32x2 frcpv (f32x2 v){ return (f32x2){frcpf(v[0]),  frcpf(v[1])};  }

__device__ __forceinline__ half2v pkrtz(float a, float b) {
    fp16x2 r = __builtin_amdgcn_cvt_pkrtz(a, b);
    return __builtin_bit_cast(half2v, r);
}

// exact fp32 -> (hi, lo): hi = v with low 13 mantissa bits cleared (11 sig
// bits -> exact in fp16), lo = v - hi (exact; |lo| <= 2^-11 |v|).
__device__ __forceinline__ float himask(float v) {
    return __builtin_bit_cast(float, __builtin_bit_cast(unsigned int, v) & 0xFFFFE000u);
}

// A-fragment prep: mask-split (hi = masked, lo = exact residual), pkrtz pack.
// IDENTICAL elementwise ops to R13.
__device__ __forceinline__ void prep_frags(const float* p32, const float* p16,
                                           half8v& ah32, half8v& al32,
                                           half4v& ah16, half4v& al16)
{
    f32x4 hv0 = *reinterpret_cast<const f32x4*>(p32);
    f32x4 hv1 = *reinterpret_cast<const f32x4*>(p32 + 4);
    f32x4 hv2 = *reinterpret_cast<const f32x4*>(p16);

    f32x4 hi0, hi1, hi2;
#pragma unroll
    for (int j = 0; j < 4; ++j) {
        hi0[j] = himask(hv0[j]);
        hi1[j] = himask(hv1[j]);
        hi2[j] = himask(hv2[j]);
    }
    f32x4 lo0 = hv0 - hi0;
    f32x4 lo1 = hv1 - hi1;
    f32x4 lo2 = hv2 - hi2;

    half2v h00 = pkrtz(hi0[0], hi0[1]);
    half2v h01 = pkrtz(hi0[2], hi0[3]);
    half2v h10 = pkrtz(hi1[0], hi1[1]);
    half2v h11 = pkrtz(hi1[2], hi1[3]);
    half2v l00 = pkrtz(lo0[0], lo0[1]);
    half2v l01 = pkrtz(lo0[2], lo0[3]);
    half2v l10 = pkrtz(lo1[0], lo1[1]);
    half2v l11 = pkrtz(lo1[2], lo1[3]);
    half2v h20 = pkrtz(hi2[0], hi2[1]);
    half2v h21 = pkrtz(hi2[2], hi2[3]);
    half2v l20 = pkrtz(lo2[0], lo2[1]);
    half2v l21 = pkrtz(lo2[2], lo2[3]);

    half4v a0 = __builtin_shufflevector(h00, h01, 0, 1, 2, 3);
    half4v a1 = __builtin_shufflevector(h10, h11, 0, 1, 2, 3);
    ah32 = __builtin_shufflevector(a0, a1, 0, 1, 2, 3, 4, 5, 6, 7);
    half4v b0 = __builtin_shufflevector(l00, l01, 0, 1, 2, 3);
    half4v b1 = __builtin_shufflevector(l10, l11, 0, 1, 2, 3);
    al32 = __builtin_shufflevector(b0, b1, 0, 1, 2, 3, 4, 5, 6, 7);
    ah16 = __builtin_shufflevector(h20, h21, 0, 1, 2, 3);
    al16 = __builtin_shufflevector(l20, l21, 0, 1, 2, 3);
}

// packed activations over r-pairs. IDENTICAL elementwise ops to R13.
//   cn = [c(1+e_i)(1+E_g) + (E_g-1)(1+e_f)] / [(1+e_i)(1+E_g)(1+e_f)]
//   hn = (E_c-1) / [(1+e_o)(1+E_c)]
__device__ __forceinline__ void gates_act(const f32x4& ai, const f32x4& af,
                                          const f32x4& ag, const f32x4& ao,
                                          f32x2 (&cst)[2],
                                          float* wb, float* wb2, const int jt)
{
#pragma unroll
    for (int p = 0; p < 2; ++p) {
        const f32x2 yi = (f32x2){ai[2*p], ai[2*p+1]};
        const f32x2 yf = (f32x2){af[2*p], af[2*p+1]};
        const f32x2 yg = (f32x2){ag[2*p], ag[2*p+1]};
        const f32x2 yo = (f32x2){ao[2*p], ao[2*p+1]};
        const f32x2 ei = fexp2v(yi);
        const f32x2 ef = fexp2v(yf);
        const f32x2 Eg = fexp2v(yg);
        const f32x2 eo = fexp2v(yo);
        const f32x2 one = (f32x2){1.0f, 1.0f};
        const f32x2 u_ = one + ei;
        const f32x2 v_ = one + Eg;
        const f32x2 w_ = one + ef;
        const f32x2 p_ = u_ * v_;
        const f32x2 q_ = (Eg - one) * w_;
        const f32x2 num = cst[p] * p_ + q_;
        const f32x2 cn  = num * frcpv(p_ * w_);
        cst[p] = cn;
        const f32x2 Ec = fexp2v(cn * (f32x2){2.0f*LOG2E, 2.0f*LOG2E});
        const f32x2 hn = (Ec - one) * frcpv((one + eo) * (one + Ec));
        if (jt < 2) {
            wb [(2*p)   * LROW + jt * 16] = hn[0];
            wb [(2*p+1) * LROW + jt * 16] = hn[1];
        } else {
            wb2[(2*p)   * LROW + 32]      = hn[0];
            wb2[(2*p+1) * LROW + 32]      = hn[1];
        }
    }
}

__global__ __launch_bounds__(BLK, 1)
void lstm_mfma_kernel(const float* __restrict__ x,
                      const float* __restrict__ W_ih,   // (160,1)
                      const float* __restrict__ W_hh,   // (160,40) row-major
                      const float* __restrict__ b_ih,   // (160,)
                      const float* __restrict__ b_hh,   // (160,)
                      const float* __restrict__ W_fc,   // (4,40) row-major
                      const float* __restrict__ b_fc,   // (4,)
                      float* __restrict__ out)          // [B*4 logits][B argmax]
{
    __shared__ __align__(16) float lds[WPB * NCH * TILEF];   // 61440 B

    const int tid  = threadIdx.x;
    const int wv   = __builtin_amdgcn_readfirstlane(tid >> 6);
    const int lane = tid & 63;
    const int col  = lane & 15;        // MFMA m / n index
    const int quad = lane >> 4;        // MFMA k-group / C-row group

    float* hbase = lds + wv * (NCH * TILEF);

    // ---------------- prologue: load + scale + fp16-split B fragments ----------
    // ONE copy per wave, shared by all NCH chains (this is the whole point).
    half8v Bh32[NT], Bl32[NT];
    half4v Bh16[NT], Bl16[NT];
#pragma unroll
    for (int tau = 0; tau < NT; ++tau) {
        const int   tt    = tau / 3;                 // gate type 0:i 1:f 2:g 3:o
        const int   ubase = (tau % 3) * 16;
        const float scale = (tt == 2) ? (2.0f * LOG2E) : (-LOG2E);
        const int   u     = ubase + col;             // padded unit index (0..47)
        const bool  valid = (u < H_);
        const int   r     = tt * H_ + (valid ? u : (H_ - 1));  // clamped row

        {
            float4 w0 = *reinterpret_cast<const float4*>(W_hh + r * H_ + 8 * quad);
            float4 w1 = *reinterpret_cast<const float4*>(W_hh + r * H_ + 8 * quad + 4);
            float wa[8] = {w0.x, w0.y, w0.z, w0.w, w1.x, w1.y, w1.z, w1.w};
            half8v bh, bl;
#pragma unroll
            for (int j = 0; j < 8; ++j) {
                float w = valid ? (wa[j] * scale) : 0.0f;
                _Float16 hi = (_Float16)w;
                bh[j] = hi;
                bl[j] = (_Float16)(w - (float)hi);
            }
            Bh32[tau] = bh; Bl32[tau] = bl;
        }
        {
            float4 wv4;
            if (quad == 0)      wv4 = *reinterpret_cast<const float4*>(W_hh + r * H_ + 32);
            else if (quad == 1) wv4 = *reinterpret_cast<const float4*>(W_hh + r * H_ + 36);
            else if (quad == 2) wv4 = make_float4(W_ih[r], b_ih[r] + b_hh[r], 0.0f, 0.0f);
            else                wv4 = make_float4(0.0f, 0.0f, 0.0f, 0.0f);
            float wa[4] = {wv4.x, wv4.y, wv4.z, wv4.w};
            half4v bh, bl;
#pragma unroll
            for (int j = 0; j < 4; ++j) {
                float w = valid ? (wa[j] * scale) : 0.0f;
                _Float16 hi = (_Float16)w;
                bh[j] = hi;
                bl[j] = (_Float16)(w - (float)hi);
            }
            Bh16[tau] = bh; Bl16[tau] = bl;
        }
    }

    const f32x4 zc = (f32x4){0.f, 0.f, 0.f, 0.f};

    // ---------------- t-invariant per-lane pointers (chain offset = imm) -------
    const float* pA   = hbase + col * LROW + 8 * quad;       // K32 reads
    const float* pA16 = hbase + col * LROW + 32 + 4 * quad;  // K16 reads
    float* pX   = hbase + quad * TILEF + col * LROW + 40;    // x staging: lane
                                                             // (col,q) stages
                                                             // chain q — no branch
    float* pW   = hbase + 4 * quad * LROW + col;             // hn stores, jt=0,1
    float* pW2  = pW + ((col >= 8) ? 8 : 0);                 // hn stores, jt=2
    float* pRow = hbase + col * LROW;                        // epilogue reads

    const long wavebase = (long)blockIdx.x * SPB + (long)wv * (SPW * NGRP);

#pragma unroll 1
    for (int g = 0; g < NGRP; ++g) {
        const long gbase = wavebase + (long)g * SPW;

        // ---- re-init wave slice: zero (incl. pad cols 42..47), bias col 41 ----
        {
            f32x4* zp = reinterpret_cast<f32x4*>(hbase);
#pragma unroll
            for (int i = 0; i < (NCH * TILEF) / 4 / 64; ++i)   // 15
                zp[i * 64 + lane] = zc;
            // lane (col,quad) sets chain 'quad' bias column — all lanes useful
            hbase[quad * TILEF + col * LROW + 41] = 1.0f;
        }

        f32x2 cst2[NCH][3][2];
#pragma unroll
        for (int c = 0; c < NCH; ++c)
#pragma unroll
            for (int jt = 0; jt < 3; ++jt) {
                cst2[c][jt][0] = (f32x2){0.f, 0.f};
                cst2[c][jt][1] = (f32x2){0.f, 0.f};
            }

        // lane (col,quad) owns x for sample gbase + quad*16 + col (chain=quad)
        const float* xs = x + (long)(gbase + quad * 16 + col) * T_;
        float xv = xs[0];

        // ---------------- recurrence ----------------
#pragma unroll 1
        for (int t = 0; t < T_; ++t) {
            *pX = xv;                                  // unconditional, all lanes
            const int tn = (t + 1 < T_) ? (t + 1) : (T_ - 1);
            const float xnext = xs[tn];

            // A fragments for all chains (reads issued together -> overlap)
            half8v ah32[NCH], al32[NCH]; half4v ah16[NCH], al16[NCH];
#pragma unroll
            for (int c = 0; c < NCH; ++c)
                prep_frags(pA + c * TILEF, pA16 + c * TILEF,
                           ah32[c], al32[c], ah16[c], al16[c]);

            // 3 phases x 4 chains; chain c+1's MFMAs cover chain c's act chain
#pragma unroll
            for (int jt = 0; jt < 3; ++jt) {
#pragma unroll
                for (int c = 0; c < NCH; ++c) {
#define DOT48(tau, dst)                                                          \
                    {                                                            \
                        f32x4 a_ = __builtin_amdgcn_mfma_f32_16x16x32_f16(ah32[c], Bh32[tau], zc, 0, 0, 0); \
                        a_ = __builtin_amdgcn_mfma_f32_16x16x32_f16(al32[c], Bh32[tau], a_, 0, 0, 0); \
                        a_ = __builtin_amdgcn_mfma_f32_16x16x32_f16(ah32[c], Bl32[tau], a_, 0, 0, 0); \
                        a_ = __builtin_amdgcn_mfma_f32_16x16x16f16(ah16[c], Bh16[tau], a_, 0, 0, 0); \
                        a_ = __builtin_amdgcn_mfma_f32_16x16x16f16(al16[c], Bh16[tau], a_, 0, 0, 0); \
                        a_ = __builtin_amdgcn_mfma_f32_16x16x16f16(ah16[c], Bl16[tau], a_, 0, 0, 0); \
                        dst = a_;                                                \
                    }
                    f32x4 ai, af, ag, ao;
                    DOT48(jt,     ai)
                    DOT48(3 + jt, af)
                    DOT48(6 + jt, ag)
                    DOT48(9 + jt, ao)
#undef DOT48
                    gates_act(ai, af, ag, ao, cst2[c][jt],
                              pW + c * TILEF, pW2 + c * TILEF, jt);
                }
            }

            xv = xnext;
        }

        // ---------------- epilogue: FC + argmax (per chain) ----------------
#pragma unroll
        for (int c = 0; c < NCH; ++c) {
            float acc = b_fc[quad];
#pragma unroll
            for (int jj = 0; jj < 10; ++jj) {
                f32x4 hv = *reinterpret_cast<const f32x4*>(pRow + c * TILEF + 4 * jj);
                float4 wv4 = *reinterpret_cast<const float4*>(W_fc + quad * H_ + 4 * jj);
                acc = fmaf(hv[0], wv4.x, acc);
                acc = fmaf(hv[1], wv4.y, acc);
                acc = fmaf(hv[2], wv4.z, acc);
                acc = fmaf(hv[3], wv4.w, acc);
            }
            out[(long)(gbase + c * 16 + col) * C_ + quad] = acc;
            pRow[c * TILEF + 56 + quad] = acc;   // scratch for argmax
        }
        if (quad == 0) {
#pragma unroll
            for (int c = 0; c < NCH; ++c) {
                f32x4 lg = *reinterpret_cast<const f32x4*>(pRow + c * TILEF + 56);
                int am = 0;
                float best = lg[0];
                if (lg[1] > best) { best = lg[1]; am = 1; }
                if (lg[2] > best) { best = lg[2]; am = 2; }
                if (lg[3] > best) { best = lg[3]; am = 3; }
                out[(long)B_ * C_ + gbase + c * 16 + col] = (float)am;
            }
        }
    }
}

extern "C" void kernel_launch(void* const* d_in, const int* in_sizes, int n_in,
                              void* d_out, int out_size, void* d_ws, size_t ws_size,
                              hipStream_t stream) {
    const float* x    = (const float*)d_in[0];
    const float* W_ih = (const float*)d_in[1];
    const float* W_hh = (const float*)d_in[2];
    const float* b_ih = (const float*)d_in[3];
    const float* b_hh = (const float*)d_in[4];
    const float* W_fc = (const float*)d_in[5];
    const float* b_fc = (const float*)d_in[6];
    float* out = (float*)d_out;

    dim3 block(BLK);
    dim3 grid(B_ / SPB);   // 256 blocks = exactly 1 per CU, zero tail
    hipLaunchKernelGGL(lstm_mfma_kernel, grid, block, 0, stream,
                       x, W_ih, W_hh, b_ih, b_hh, W_fc, b_fc, out);
}

// Round 2
// 381.116 us; speedup vs baseline: 1.1976x; 1.1976x over previous
//
#include <hip/hip_runtime.h>

// B=131072 indep LSTMs, T=40, H=40, in-dim 1, FC C=4 + argmax.
// R15 = R13 structure (best: 395-411us, 2 waves/SIMD) + two cuts:
//  1) Mixed-gate remainder tiles: jt=2's 4 half-pad gate tiles -> 2 full
//     tiles T_if=[i 32-39 | f 32-39], T_go=[g | o] (col<8 / col>=8).
//     MFMA 72->60/step, trans 84->76/step, B regs 144->120. Activation
//     pairs gates across lane^8 (__shfl_xor 8); valid-lane math is
//     BIT-IDENTICAL to R13 -> absmax must stay 4.882812e-4.
//  2) LDS round-trip pipelining: next-step ds_reads for h units 0-31
//     issued after jt=1 stores (hidden under jt=2 compute); x_{t+1}
//     stored during step t so the a16 read issues right after jt=2
//     stores. Kills the ~120-150cy end-of-step LDS bubble.
// R14 lesson (446us): 1 wave/SIMD is issue-port-bound (~1 instr/2cy);
// ILP cannot replace the 2nd wave. Stay at 2 waves/SIMD.

#define B_    131072
#define T_    40
#define H_    40
#define C_    4
#define BLK   256
#define WPB   4
#define SPW   16          // samples per wave
#define SPB   64          // samples per block
#define LROW  68          // padded LDS row stride (floats); 68%32=4 -> 2-way only
#define NT    10          // 8 full gate tiles + T_if + T_go
#define LOG2E 1.44269504088896340736f

typedef __fp16   fp16x2 __attribute__((ext_vector_type(2)));
typedef _Float16 half2v __attribute__((ext_vector_type(2)));
typedef _Float16 half4v __attribute__((ext_vector_type(4)));
typedef _Float16 half8v __attribute__((ext_vector_type(8)));
typedef float    f32x2  __attribute__((ext_vector_type(2)));
typedef float    f32x4  __attribute__((ext_vector_type(4)));

__device__ __forceinline__ float fexp2f(float v){ return __builtin_amdgcn_exp2f(v); }
__device__ __forceinline__ float frcpf (float v){ return __builtin_amdgcn_rcpf(v); }

__device__ __forceinline__ f32x2 fexp2v(f32x2 v){ return (f32x2){fexp2f(v[0]), fexp2f(v[1])}; }
__device__ __forceinline__ f32x2 frcpv (f32x2 v){ return (f32x2){frcpf(v[0]),  frcpf(v[1])};  }

// lane^8 exchange within each 16-lane group (col<8 <-> col+8, same quad)
__device__ __forceinline__ f32x2 shflx8(f32x2 v){
    return (f32x2){ __shfl_xor(v[0], 8, 64), __shfl_xor(v[1], 8, 64) };
}

__device__ __forceinline__ half2v pkrtz(float a, float b) {
    fp16x2 r = __builtin_amdgcn_cvt_pkrtz(a, b);
    return __builtin_bit_cast(half2v, r);
}

// exact fp32 -> (hi, lo): hi = v with low 13 mantissa bits cleared (11 sig
// bits -> exact in fp16), lo = v - hi (exact; |lo| <= 2^-11 |v|).
__device__ __forceinline__ float himask(float v) {
    return __builtin_bit_cast(float, __builtin_bit_cast(unsigned int, v) & 0xFFFFE000u);
}

// packed activations over sample-pairs. IDENTICAL elementwise ops to R13.
//   cn = [c(1+e_i)(1+E_g) + (E_g-1)(1+e_f)] / [(1+e_i)(1+E_g)(1+e_f)]
//   hn = (E_c-1) / [(1+e_o)(1+E_c)]
__device__ __forceinline__ void gates_act(const f32x4& ai, const f32x4& af,
                                          const f32x4& ag, const f32x4& ao,
                                          f32x2 (&cst)[2],
                                          float* wb, const int jt)
{
#pragma unroll
    for (int p = 0; p < 2; ++p) {
        const f32x2 yi = (f32x2){ai[2*p], ai[2*p+1]};
        const f32x2 yf = (f32x2){af[2*p], af[2*p+1]};
        const f32x2 yg = (f32x2){ag[2*p], ag[2*p+1]};
        const f32x2 yo = (f32x2){ao[2*p], ao[2*p+1]};
        const f32x2 ei = fexp2v(yi);
        const f32x2 ef = fexp2v(yf);
        const f32x2 Eg = fexp2v(yg);
        const f32x2 eo = fexp2v(yo);
        const f32x2 one = (f32x2){1.0f, 1.0f};
        const f32x2 u_ = one + ei;
        const f32x2 v_ = one + Eg;
        const f32x2 w_ = one + ef;
        const f32x2 p_ = u_ * v_;
        const f32x2 q_ = (Eg - one) * w_;
        const f32x2 num = cst[p] * p_ + q_;
        const f32x2 cn  = num * frcpv(p_ * w_);
        cst[p] = cn;
        const f32x2 Ec = fexp2v(cn * (f32x2){2.0f*LOG2E, 2.0f*LOG2E});
        const f32x2 hn = (Ec - one) * frcpv((one + eo) * (one + Ec));
        wb[(2*p)   * LROW + jt * 16] = hn[0];
        wb[(2*p+1) * LROW + jt * 16] = hn[1];
    }
}

__global__ __launch_bounds__(BLK, 2)
void lstm_mfma_kernel(const float* __restrict__ x,
                      const float* __restrict__ W_ih,   // (160,1)
                      const float* __restrict__ W_hh,   // (160,40) row-major
                      const float* __restrict__ b_ih,   // (160,)
                      const float* __restrict__ b_hh,   // (160,)
                      const float* __restrict__ W_fc,   // (4,40) row-major
                      const float* __restrict__ b_fc,   // (4,)
                      float* __restrict__ out)          // [B*4 logits][B argmax]
{
    __shared__ float lds[WPB * SPW * LROW];

    const int tid  = threadIdx.x;
    const int wv   = __builtin_amdgcn_readfirstlane(tid >> 6);
    const int lane = tid & 63;
    const int col  = lane & 15;        // MFMA n index (= unit within tile)
    const int quad = lane >> 4;        // MFMA k-group / sample-group
    const int sbase = blockIdx.x * SPB + wv * SPW;

    float* hbase = lds + wv * (SPW * LROW);

    // ---------------- prologue: zero LDS slice, bias-one column ----------------
#pragma unroll
    for (int i = 0; i < (SPW * LROW) / 64; ++i)     // 1088/64 = 17
        hbase[i * 64 + lane] = 0.0f;
    if (quad == 0) hbase[col * LROW + 41] = 1.0f;   // h_aug[m][41] = 1.0 (bias)

    // ---------------- prologue: load + scale + fp16-split B fragments ----------
    // 10 tiles: tau 0..7 = (gate tt = tau>>1, unit-group jt = tau&1, all valid);
    // tau 8 = T_if (i|f units 32-39), tau 9 = T_go (g|o units 32-39).
    half8v Bh32[NT], Bl32[NT];
    half4v Bh16[NT], Bl16[NT];
#pragma unroll
    for (int tau = 0; tau < NT; ++tau) {
        int   r;
        float scale;
        if (tau < 8) {
            const int tt = tau >> 1;
            const int jt = tau & 1;
            r     = tt * H_ + jt * 16 + col;                    // u <= 31 < 40
            scale = (tt == 2) ? (2.0f * LOG2E) : (-LOG2E);
        } else if (tau == 8) {                                  // T_if
            r     = (col < 8) ? (32 + col) : (H_ + 32 + (col - 8));
            scale = -LOG2E;
        } else {                                                // T_go
            r     = (col < 8) ? (2 * H_ + 32 + col) : (3 * H_ + 32 + (col - 8));
            scale = (col < 8) ? (2.0f * LOG2E) : (-LOG2E);
        }

        {
            float4 w0 = *reinterpret_cast<const float4*>(W_hh + r * H_ + 8 * quad);
            float4 w1 = *reinterpret_cast<const float4*>(W_hh + r * H_ + 8 * quad + 4);
            float wa[8] = {w0.x, w0.y, w0.z, w0.w, w1.x, w1.y, w1.z, w1.w};
            half8v bh, bl;
#pragma unroll
            for (int j = 0; j < 8; ++j) {
                float w = wa[j] * scale;
                _Float16 hi = (_Float16)w;
                bh[j] = hi;
                bl[j] = (_Float16)(w - (float)hi);
            }
            Bh32[tau] = bh; Bl32[tau] = bl;
        }
        {
            float4 wv4;
            if (quad == 0)      wv4 = *reinterpret_cast<const float4*>(W_hh + r * H_ + 32);
            else if (quad == 1) wv4 = *reinterpret_cast<const float4*>(W_hh + r * H_ + 36);
            else if (quad == 2) wv4 = make_float4(W_ih[r], b_ih[r] + b_hh[r], 0.0f, 0.0f);
            else                wv4 = make_float4(0.0f, 0.0f, 0.0f, 0.0f);
            float wa[4] = {wv4.x, wv4.y, wv4.z, wv4.w};
            half4v bh, bl;
#pragma unroll
            for (int j = 0; j < 4; ++j) {
                float w = wa[j] * scale;
                _Float16 hi = (_Float16)w;
                bh[j] = hi;
                bl[j] = (_Float16)(w - (float)hi);
            }
            Bh16[tau] = bh; Bl16[tau] = bl;
        }
    }

    // cell state: cst2[jt][p] = c for sample-pair p of unit-group jt
    // (jt=2 valid on col<8 lanes only; col>=8 lanes carry inert garbage)
    f32x2 cst2[3][2];
#pragma unroll
    for (int jt = 0; jt < 3; ++jt) {
        cst2[jt][0] = (f32x2){0.f, 0.f};
        cst2[jt][1] = (f32x2){0.f, 0.f};
    }

    const f32x4 zc = (f32x4){0.f, 0.f, 0.f, 0.f};

    // ---------------- t-invariant LDS pointers ----------------
    const float* myrow = hbase + col * LROW;            // A-frag row (sample=col)
    const float* a32p  = myrow + 8 * quad;              // K32 reads: cols 8q..8q+7
    const float* a16p  = myrow + 32 + 4 * quad;         // K16 reads: cols 32+4q..
    float* xslot  = hbase + col * LROW + 40;            // x staging (quad 0)
    float* wbase  = hbase + 4 * quad * LROW + col;      // hn stores, jt=0,1
    float* wbase2 = wbase + ((col >= 8) ? 8 : 0) + 32;  // hn stores, jt=2 (dump 48-55 for col>=8)

    const float* xrow = x + (long)(sbase + col) * T_;
    float xv = xrow[0];
    if (quad == 0) *xslot = xv;                         // x_0

    // prime the pipelined A-reads (h=0 + x_0 + bias)
    f32x4 hv0 = *reinterpret_cast<const f32x4*>(a32p);
    f32x4 hv1 = *reinterpret_cast<const f32x4*>(a32p + 4);
    f32x4 hv2 = *reinterpret_cast<const f32x4*>(a16p);

    // ---------------- recurrence ----------------
#pragma unroll 1
    for (int t = 0; t < T_; ++t) {
        const int tn = (t + 1 < T_) ? (t + 1) : (T_ - 1);
        const float xnext = xrow[tn];

        // A fragments from the in-flight reads: mask-split + pkrtz pack
        half8v ah32, al32; half4v ah16, al16;
        {
            f32x4 hi0, hi1, hi2;
#pragma unroll
            for (int j = 0; j < 4; ++j) {
                hi0[j] = himask(hv0[j]);
                hi1[j] = himask(hv1[j]);
                hi2[j] = himask(hv2[j]);
            }
            f32x4 lo0 = hv0 - hi0;
            f32x4 lo1 = hv1 - hi1;
            f32x4 lo2 = hv2 - hi2;

            half2v h00 = pkrtz(hi0[0], hi0[1]);
            half2v h01 = pkrtz(hi0[2], hi0[3]);
            half2v h10 = pkrtz(hi1[0], hi1[1]);
            half2v h11 = pkrtz(hi1[2], hi1[3]);
            half2v l00 = pkrtz(lo0[0], lo0[1]);
            half2v l01 = pkrtz(lo0[2], lo0[3]);
            half2v l10 = pkrtz(lo1[0], lo1[1]);
            half2v l11 = pkrtz(lo1[2], lo1[3]);
            half2v h20 = pkrtz(hi2[0], hi2[1]);
            half2v h21 = pkrtz(hi2[2], hi2[3]);
            half2v l20 = pkrtz(lo2[0], lo2[1]);
            half2v l21 = pkrtz(lo2[2], lo2[3]);

            half4v a0 = __builtin_shufflevector(h00, h01, 0, 1, 2, 3);
            half4v a1 = __builtin_shufflevector(h10, h11, 0, 1, 2, 3);
            ah32 = __builtin_shufflevector(a0, a1, 0, 1, 2, 3, 4, 5, 6, 7);
            half4v b0 = __builtin_shufflevector(l00, l01, 0, 1, 2, 3);
            half4v b1 = __builtin_shufflevector(l10, l11, 0, 1, 2, 3);
            al32 = __builtin_shufflevector(b0, b1, 0, 1, 2, 3, 4, 5, 6, 7);
            ah16 = __builtin_shufflevector(h20, h21, 0, 1, 2, 3);
            al16 = __builtin_shufflevector(l20, l21, 0, 1, 2, 3);
        }

#define DOT48(tau, dst)                                                          \
        {                                                                        \
            f32x4 a_ = __builtin_amdgcn_mfma_f32_16x16x32_f16(ah32, Bh32[tau], zc, 0, 0, 0); \
            a_ = __builtin_amdgcn_mfma_f32_16x16x32_f16(al32, Bh32[tau], a_, 0, 0, 0); \
            a_ = __builtin_amdgcn_mfma_f32_16x16x32_f16(ah32, Bl32[tau], a_, 0, 0, 0); \
            a_ = __builtin_amdgcn_mfma_f32_16x16x16f16(ah16, Bh16[tau], a_, 0, 0, 0); \
            a_ = __builtin_amdgcn_mfma_f32_16x16x16f16(al16, Bh16[tau], a_, 0, 0, 0); \
            a_ = __builtin_amdgcn_mfma_f32_16x16x16f16(ah16, Bl16[tau], a_, 0, 0, 0); \
            dst = a_;                                                            \
        }

        // ---- full unit-groups jt = 0,1 (4 gate tiles each) ----
#pragma unroll
        for (int jt = 0; jt < 2; ++jt) {
            f32x4 ai, af, ag, ao;
            DOT48(0 + jt, ai)
            DOT48(2 + jt, af)
            DOT48(4 + jt, ag)
            DOT48(6 + jt, ao)
            gates_act(ai, af, ag, ao, cst2[jt], wbase, jt);
        }

        // issue next-step A-reads for h units 0-31 (just written above);
        // their latency hides under the jt=2 MFMAs + activation below
        hv0 = *reinterpret_cast<const f32x4*>(a32p);
        hv1 = *reinterpret_cast<const f32x4*>(a32p + 4);

        // ---- remainder unit-group jt=2: mixed tiles T_if, T_go ----
        {
            f32x4 aif, ago;
            DOT48(8, aif)
            DOT48(9, ago)
#pragma unroll
            for (int p = 0; p < 2; ++p) {
                const f32x2 y1 = (f32x2){aif[2*p], aif[2*p+1]};   // i | f
                const f32x2 y2 = (f32x2){ago[2*p], ago[2*p+1]};   // g | o
                const f32x2 e1 = fexp2v(y1);                      // ei | ef
                const f32x2 e2 = fexp2v(y2);                      // Eg | eo
                const f32x2 one = (f32x2){1.0f, 1.0f};
                const f32x2 s1 = one + e1;                        // u_ | w_
                const f32x2 s2 = one + e2;                        // v_ | 1+eo
                const f32x2 w_ = shflx8(s1);                      // w_ | u_
                const f32x2 oe = shflx8(s2);                      // 1+eo | v_
                const f32x2 p_ = s1 * s2;                         // u_*v_ | (junk)
                const f32x2 q_ = (e2 - one) * w_;                 // (Eg-1)*w_ | (junk)
                const f32x2 num = cst2[2][p] * p_ + q_;
                const f32x2 cn  = num * frcpv(p_ * w_);
                cst2[2][p] = cn;
                const f32x2 Ec = fexp2v(cn * (f32x2){2.0f*LOG2E, 2.0f*LOG2E});
                const f32x2 hn = (Ec - one) * frcpv(oe * (one + Ec));
                // col<8: h[sample][32+col]; col>=8: dump cols 48-55 (never read)
                wbase2[(2*p)   * LROW] = hn[0];
                wbase2[(2*p+1) * LROW] = hn[1];
            }
        }

        // stage x_{t+1}, then issue the K16 read (cols 32-47 incl x,bias)
        if (quad == 0) *xslot = xnext;
        hv2 = *reinterpret_cast<const f32x4*>(a16p);
#undef DOT48
    }

    // ---------------- epilogue: FC + argmax ----------------
    {
        float acc = b_fc[quad];
#pragma unroll
        for (int jj = 0; jj < 10; ++jj) {
            f32x4 hv = *reinterpret_cast<const f32x4*>(myrow + 4 * jj);
            float4 wv4 = *reinterpret_cast<const float4*>(W_fc + quad * H_ + 4 * jj);
            acc = fmaf(hv[0], wv4.x, acc);
            acc = fmaf(hv[1], wv4.y, acc);
            acc = fmaf(hv[2], wv4.z, acc);
            acc = fmaf(hv[3], wv4.w, acc);
        }
        out[(long)(sbase + col) * C_ + quad] = acc;
        hbase[col * LROW + 56 + quad] = acc;   // scratch for argmax
    }
    if (quad == 0) {
        f32x4 lg = *reinterpret_cast<const f32x4*>(hbase + col * LROW + 56);
        int am = 0;
        float best = lg[0];
        if (lg[1] > best) { best = lg[1]; am = 1; }
        if (lg[2] > best) { best = lg[2]; am = 2; }
        if (lg[3] > best) { best = lg[3]; am = 3; }
        out[(long)B_ * C_ + sbase + col] = (float)am;
    }
}

extern "C" void kernel_launch(void* const* d_in, const int* in_sizes, int n_in,
                              void* d_out, int out_size, void* d_ws, size_t ws_size,
                              hipStream_t stream) {
    const float* x    = (const float*)d_in[0];
    const float* W_ih = (const float*)d_in[1];
    const float* W_hh = (const float*)d_in[2];
    const float* b_ih = (const float*)d_in[3];
    const float* b_hh = (const float*)d_in[4];
    const float* W_fc = (const float*)d_in[5];
    const float* b_fc = (const float*)d_in[6];
    float* out = (float*)d_out;

    dim3 block(BLK);
    dim3 grid(B_ / SPB);
    hipLaunchKernelGGL(lstm_mfma_kernel, grid, block, 0, stream,
                       x, W_ih, W_hh, b_ih, b_hh, W_fc, b_fc, out);
}